// Round 2
// 281.909 us; speedup vs baseline: 1.0372x; 1.0372x over previous
//
#include <hip/hip_runtime.h>
#include <hip/hip_bf16.h>
#include <math.h>

// T=4096, B=4, S=16 -> BS=64, F=64, CH=97 (16 B | 16 C | 1 A | 64 X), K=5.
// Output: (T, B, S) float32, flat index t*64 + bs.
//
// ROUND 11 (latency attack on k_conv):
//  - launch_bounds(256,4): 128-VGPR budget (was 56 -> load-serialized K loop),
//    full unroll, 10 loads batched per K-step so they pipeline.
//  - Dx folded into the GEMM as channel 97 (pass_w at tap k=4) -> whole Dx
//    LDS pass + reduction + barrier deleted; comes free out of the ct6 tile.
//  - zAS/fac/redd/redx LDS arrays and 3 of 4 barriers replaced by in-wave
//    __shfl broadcast (A rows live in the same wave) and __shfl_xor
//    reductions over the 16 'n' lanes. k_conv has ONE __syncthreads now.
//  - dead pad-column zeroing dropped (cols 64..71 never read: f0+8 <= 64).
//  - k_scan: serial 64-step scan (latency-bound, GPU idle) -> wave-parallel
//    composition scan, one wave per (bs,n), 6 shfl_up steps.
//  - k_chunk: 4 chunks per 256-thread block (was 1-wave blocks).

#define Tn 4096
#define BSn 64
#define Fn 64
#define CHn 97
#define CHP 112   // padded channels for MFMA (7 tiles of 16); ch97 = pass_w@k4
#define Kn 5
#define Nn 16
#define NCn 64

typedef __attribute__((ext_vector_type(8))) short bf16x8;
typedef __attribute__((ext_vector_type(4))) float f32x4;

static __device__ __forceinline__ unsigned short f2bf(float v) {
    __hip_bfloat16 b = __float2bfloat16(v);
    return *reinterpret_cast<unsigned short*>(&b);
}
static __device__ __forceinline__ float bf2f(unsigned short u) {
    unsigned v = ((unsigned)u) << 16;
    return __builtin_bit_cast(float, v);
}

// ---------------- workspace layout (float units) ----------------
// end = OFF_WBL + 2560 = 9,592,832 fl = 38,371,328 B < round-1-validated
// 38,413,568 B envelope (hard bound).
#define OFF_BD   0
#define OFF_CM   (OFF_BD + 4194304)
#define OFF_LAD  (OFF_CM + 4194304)
#define OFF_XQ   (OFF_LAD + 262144)
#define OFF_DL   (OFF_XQ + 262144)
#define OFF_ACS  (OFF_DL + 262144)
#define OFF_SRED (OFF_ACS + 262144)
#define OFF_CSUM (OFF_SRED + 65536)
#define OFF_SNS  (OFF_CSUM + 4096)
#define OFF_WBH  (OFF_SNS + 65536)      // bf16 [k][112][64]
#define OFF_WBL  (OFF_WBH + 17920)      // bf16 lo-residual [k][16][64] (ch32..47)

// K0: weight prep. ch<97: conv_w; ch97,k=4: pass_w (Dx-as-GEMM row); else 0.
__global__ __launch_bounds__(256) void k_prep(const float* __restrict__ conv_w,
                                              const float* __restrict__ pass_w,
                                              unsigned short* __restrict__ wbh,
                                              unsigned short* __restrict__ wbl) {
    int idx = blockIdx.x * 256 + threadIdx.x;
    if (idx >= Kn * CHP * Fn) return;
    int f = idx & 63;
    int rest = idx >> 6;
    int ch = rest % CHP;
    int k = rest / CHP;
    float w = 0.f;
    if (ch < CHn) w = conv_w[(ch * Fn + f) * Kn + k];
    else if (ch == 97 && k == 4) w = pass_w[f];
    unsigned short hi = f2bf(w);
    wbh[idx] = hi;
    if (ch >= 32 && ch < 48)
        wbl[(k * 16 + (ch - 32)) * 64 + f] = f2bf(w - bf2f(hi));
}

// K1: MFMA conv (97 real ch + Dx ch97; ct2 split-corrected), epilogue fully
// in registers/shuffles. One block = (ci, bs), 256 thr = 4 waves; wave wv
// owns output rows 16wv..16wv+15. ONE barrier.
__global__ __launch_bounds__(256, 4) void k_conv(
    const float* __restrict__ x, const unsigned short* __restrict__ wbh,
    const unsigned short* __restrict__ wbl,
    const float* __restrict__ conv_b, const float* __restrict__ pass_b,
    const float* __restrict__ red_w, const float* __restrict__ red_b,
    const float* __restrict__ dtp,
    float* __restrict__ Bd_t, float* __restrict__ Cm_t,
    float* __restrict__ lAd_ws, float* __restrict__ xq_ws,
    float* __restrict__ DL_ws) {
    const int ci = blockIdx.x, bs = blockIdx.y;
    const int tid = threadIdx.x;
    const int wv = tid >> 6, lane = tid & 63;
    const int qd = lane >> 4, n = lane & 15;

    __shared__ alignas(16) unsigned short xsb[68 * 72];  // bf16 hi, pitch 72
    __shared__ alignas(16) unsigned short xlo[68 * 72];  // bf16 lo residual

    // ---- batched staging: 5 independent float4 loads -> one wait -> store
    float4 v[5];
#pragma unroll
    for (int it = 0; it < 5; ++it) {
        int idx = tid + it * 256;
        int tt = idx >> 4, fq = (idx & 15) * 4;
        int t = ci * 64 - 4 + tt;
        v[it] = (idx < 68 * 16 && t >= 0)
                    ? *(const float4*)&x[(t * 64 + bs) * 64 + fq]
                    : make_float4(0.f, 0.f, 0.f, 0.f);
    }
#pragma unroll
    for (int it = 0; it < 5; ++it) {
        int idx = tid + it * 256;
        if (idx < 68 * 16) {
            int tt = idx >> 4, fq = (idx & 15) * 4;
            ushort4 h, lo;
            h.x = f2bf(v[it].x); lo.x = f2bf(v[it].x - bf2f(h.x));
            h.y = f2bf(v[it].y); lo.y = f2bf(v[it].y - bf2f(h.y));
            h.z = f2bf(v[it].z); lo.z = f2bf(v[it].z - bf2f(h.z));
            h.w = f2bf(v[it].w); lo.w = f2bf(v[it].w - bf2f(h.w));
            *(ushort4*)&xsb[tt * 72 + fq] = h;
            *(ushort4*)&xlo[tt * 72 + fq] = lo;
        }
    }
    __syncthreads();  // the only barrier in this kernel

    // ---- MFMA GEMM (HW-verified fragment path): K = 5 taps x 64 f.
    // All 10 loads of a K-step issued before its MFMAs; full unroll lets the
    // scheduler keep the next step's loads in flight (128-VGPR budget).
    f32x4 acc[7];
#pragma unroll
    for (int ct = 0; ct < 7; ++ct) acc[ct] = (f32x4){0.f, 0.f, 0.f, 0.f};
#pragma unroll
    for (int s = 0; s < 10; ++s) {
        const int k = s >> 1;
        const int f0 = 32 * (s & 1) + qd * 8;
        bf16x8 av = *(const bf16x8*)&xsb[(16 * wv + n + k) * 72 + f0];
        bf16x8 al = *(const bf16x8*)&xlo[(16 * wv + n + k) * 72 + f0];
        bf16x8 bl2 = *(const bf16x8*)&wbl[((k * 16 + n) << 6) + f0];
        bf16x8 bv[7];
#pragma unroll
        for (int ct = 0; ct < 7; ++ct)
            bv[ct] = *(const bf16x8*)&wbh[((k * CHP + 16 * ct + n) << 6) + f0];
#pragma unroll
        for (int ct = 0; ct < 7; ++ct)
            acc[ct] = __builtin_amdgcn_mfma_f32_16x16x32_bf16(av, bv[ct], acc[ct], 0, 0, 0);
        // split-residual correction for ct2 tile (ch 32..47): A channel
        // ~f32-exact; drops only x_lo*w_lo (~2^-18 rel).
        acc[2] = __builtin_amdgcn_mfma_f32_16x16x32_bf16(al, bv[2], acc[2], 0, 0, 0);
        acc[2] = __builtin_amdgcn_mfma_f32_16x16x32_bf16(av, bl2, acc[2], 0, 0, 0);
    }

    // ---- A transform via in-wave broadcast (A rows = ct2 col n==0; D layout
    // row = 16wv+4qd+reg, col = n -> source lane qd*16 within this wave).
    const int l0 = 16 * wv + 4 * qd;
    const float dt = log1pf(expf(dtp[0])) + 0.01f;
    const float cb32 = conv_b[32];
    float fac_r[4];
#pragma unroll
    for (int reg = 0; reg < 4; ++reg) {
        float zA = __shfl(acc[2][reg], lane & 48, 64) + cb32;
        float a = zA + 1.f / (1.f + __expf(-zA));
        float An = -fabsf(a);
        float lAd = dt * An;
        if (n == 0) lAd_ws[bs * Tn + ci * 64 + l0 + reg] = lAd;
        fac_r[reg] = (__expf(lAd) - 1.f) / (An + 1e-9f);
    }

    // ---- epilogue from acc regs: lane owns col ch=16ct+n, rows l0+reg
    float px[4] = {0.f, 0.f, 0.f, 0.f};
#pragma unroll
    for (int ct = 0; ct < 7; ++ct) {
        int ch = 16 * ct + n;
        float cb = (ch < CHn) ? conv_b[ch] : 0.f;
        float rw = (ch >= 33 && ch < CHn) ? red_w[ch - 33] : 0.f;
#pragma unroll
        for (int reg = 0; reg < 4; ++reg) {
            float z = acc[ct][reg] + cb;
            float a = z + 1.f / (1.f + __expf(-z));
            if (ct == 0) {
                Bd_t[((bs * 64 + ci) * 64 + l0 + reg) * 16 + n] = a * fac_r[reg];
            } else if (ct == 1) {
                Cm_t[((bs * 64 + ci) * 64 + l0 + reg) * 16 + n] = a;
            } else {
                px[reg] += a * rw;  // rw==0 for ch32 (A), ch>=97
            }
        }
    }
    // Dx = ct6 col n==1 (channel 97), raw (no conv activation, cb==0)
    if (n == 1) {
        const float pb = pass_b[0], rb = red_b[0];
#pragma unroll
        for (int reg = 0; reg < 4; ++reg) {
            float Dx = acc[6][reg] + pb;
            float DL = (Dx >= 0.f) ? Dx : 0.01f * Dx;
            DL_ws[bs * Tn + ci * 64 + l0 + reg] = DL + rb;
        }
    }
    // xq: reduce px over the 16 'n' lanes of each quarter-wave
#pragma unroll
    for (int m = 1; m < 16; m <<= 1) {
#pragma unroll
        for (int reg = 0; reg < 4; ++reg)
            px[reg] += __shfl_xor(px[reg], m, 64);
    }
    if (n == 0) {
#pragma unroll
        for (int reg = 0; reg < 4; ++reg)
            xq_ws[bs * Tn + ci * 64 + l0 + reg] = px[reg];
    }
}

// K2: per (bs, ci): cumsum of lAd, decay-weighted reduced chunk state.
// Validated round-8 logic verbatim; 4 chunks per block (wave wv = chunk).
__global__ __launch_bounds__(256) void k_chunk(
    const float* __restrict__ lAd_ws, const float* __restrict__ xq_ws,
    const float* __restrict__ Bd_t, float* __restrict__ Acs_ws,
    float* __restrict__ sred_ws, float* __restrict__ csum_ws) {
    const int bs = blockIdx.y;
    const int tid = threadIdx.x, wv = tid >> 6, l = tid & 63;
    const int ci = blockIdx.x * 4 + wv;
    __shared__ float aL[4][64], acs[4][64], vv[4][64];
    __shared__ float Bt[4][64 * 17], part[4][4][16];
    const int base = bs * Tn + ci * 64;

    aL[wv][l] = lAd_ws[base + l];
    const float4* brow = (const float4*)&Bd_t[((bs * 64 + ci) * 64 + l) * 16];
    float4 b0 = brow[0], b1 = brow[1], b2 = brow[2], b3 = brow[3];
    float* bt = &Bt[wv][l * 17];
    bt[0] = b0.x;  bt[1] = b0.y;  bt[2] = b0.z;  bt[3] = b0.w;
    bt[4] = b1.x;  bt[5] = b1.y;  bt[6] = b1.z;  bt[7] = b1.w;
    bt[8] = b2.x;  bt[9] = b2.y;  bt[10] = b2.z; bt[11] = b2.w;
    bt[12] = b3.x; bt[13] = b3.y; bt[14] = b3.z; bt[15] = b3.w;
    __syncthreads();

    float s = 0.f;
    for (int k2 = 0; k2 < 64; ++k2) {
        float a = aL[wv][k2];
        if (k2 <= l) s += a;
    }
    acs[wv][l] = s;
    Acs_ws[base + l] = s;
    __syncthreads();

    float tot = acs[wv][63];
    float ds = __expf(fmaxf(tot - s, -20.f));
    vv[wv][l] = ds * xq_ws[base + l];
    __syncthreads();

    int nn = l & 15, q = l >> 4;
    float p = 0.f;
#pragma unroll
    for (int i = 0; i < 16; ++i)
        p += Bt[wv][(q * 16 + i) * 17 + nn] * vv[wv][q * 16 + i];
    part[wv][q][nn] = p;
    __syncthreads();
    if (l < 16)
        sred_ws[(bs * 64 + ci) * 16 + l] =
            part[wv][0][l] + part[wv][1][l] + part[wv][2][l] + part[wv][3][l];
    if (l == 0) csum_ws[bs * 64 + ci] = tot;
}

// K3: inter-chunk scan, wave-parallel. One wave per (bs,n) scan lane; lane ci
// holds the affine map f_ci(x) = d*x + s; 6-step shfl_up composition scan.
// sns[ci] = exclusive prefix applied to 0 (matches serial recurrence).
__global__ __launch_bounds__(256) void k_scan(const float* __restrict__ sred_ws,
                                              const float* __restrict__ csum_ws,
                                              float* __restrict__ sns_ws) {
    const int wid = blockIdx.x * 4 + (threadIdx.x >> 6);  // 0..1023
    const int ci = threadIdx.x & 63;
    const int bs = wid >> 4, n = wid & 15;
    float s = sred_ws[(bs * 64 + ci) * 16 + n];
    float d = __expf(csum_ws[bs * 64 + ci]);  // <= 1 (csum <= 0), no overflow
#pragma unroll
    for (int k = 1; k < 64; k <<= 1) {
        float dp = __shfl_up(d, k, 64);
        float sp = __shfl_up(s, k, 64);
        if (ci >= k) {
            s = d * sp + s;  // compose on top of lower segment (old d!)
            d = d * dp;
        }
    }
    float se = __shfl_up(s, 1, 64);
    sns_ws[(bs * 64 + ci) * 16 + n] = (ci == 0) ? 0.f : se;
}

// K4: y[l] = sum_m L[l,m]*(C[l]·B[m])*xq[m] + exp(Acs[l])*(C[l]·sns) + DL
//     (validated, unchanged)
__global__ __launch_bounds__(256) void k_y(
    const float* __restrict__ Cm_t, const float* __restrict__ Bd_t,
    const float* __restrict__ xq_ws, const float* __restrict__ Acs_ws,
    const float* __restrict__ sns_ws, const float* __restrict__ DL_ws,
    float* __restrict__ out) {
    const int bs = blockIdx.y;
    const int tid = threadIdx.x;
    const int wv = tid >> 6, l = tid & 63;
    const int ci = blockIdx.x * 4 + wv;
    __shared__ float Bt[4][64 * 17], xv[4][64], ac[4][64], sn[4][16];
    const int base = bs * Tn + ci * 64;

    xv[wv][l] = xq_ws[base + l];
    ac[wv][l] = Acs_ws[base + l];
    if (l < 16) sn[wv][l] = sns_ws[(bs * 64 + ci) * 16 + l];
    const float4* brow = (const float4*)&Bd_t[((bs * 64 + ci) * 64 + l) * 16];
    float4 b0 = brow[0], b1 = brow[1], b2 = brow[2], b3 = brow[3];
    float* bt = &Bt[wv][l * 17];
    bt[0] = b0.x;  bt[1] = b0.y;  bt[2] = b0.z;  bt[3] = b0.w;
    bt[4] = b1.x;  bt[5] = b1.y;  bt[6] = b1.z;  bt[7] = b1.w;
    bt[8] = b2.x;  bt[9] = b2.y;  bt[10] = b2.z; bt[11] = b2.w;
    bt[12] = b3.x; bt[13] = b3.y; bt[14] = b3.z; bt[15] = b3.w;
    const float4* crow = (const float4*)&Cm_t[((bs * 64 + ci) * 64 + l) * 16];
    float4 c0 = crow[0], c1 = crow[1], c2 = crow[2], c3 = crow[3];
    __syncthreads();

    const float acl = ac[wv][l];
    float y = 0.f;
    for (int m = 0; m < 64; ++m) {
        const float* br = &Bt[wv][m * 17];
        float g = c0.x * br[0] + c0.y * br[1] + c0.z * br[2] + c0.w * br[3] +
                  c1.x * br[4] + c1.y * br[5] + c1.z * br[6] + c1.w * br[7] +
                  c2.x * br[8] + c2.y * br[9] + c2.z * br[10] + c2.w * br[11] +
                  c3.x * br[12] + c3.y * br[13] + c3.z * br[14] + c3.w * br[15];
        float arg = (m <= l) ? fmaxf(acl - ac[wv][m], -20.f) : -20.f;
        y += __expf(arg) * g * xv[wv][m];
    }
    const float* s = sn[wv];
    float go = c0.x * s[0] + c0.y * s[1] + c0.z * s[2] + c0.w * s[3] +
               c1.x * s[4] + c1.y * s[5] + c1.z * s[6] + c1.w * s[7] +
               c2.x * s[8] + c2.y * s[9] + c2.z * s[10] + c2.w * s[11] +
               c3.x * s[12] + c3.y * s[13] + c3.z * s[14] + c3.w * s[15];
    y += __expf(acl) * go;

    out[(ci * 64 + l) * 64 + bs] = y + DL_ws[base + l];
}

extern "C" void kernel_launch(void* const* d_in, const int* in_sizes, int n_in,
                              void* d_out, int out_size, void* d_ws,
                              size_t ws_size, hipStream_t stream) {
    const float* x = (const float*)d_in[0];
    const float* conv_w = (const float*)d_in[1];
    const float* conv_b = (const float*)d_in[2];
    const float* pass_w = (const float*)d_in[3];
    const float* pass_b = (const float*)d_in[4];
    const float* red_w = (const float*)d_in[5];
    const float* red_b = (const float*)d_in[6];
    const float* dtp = (const float*)d_in[7];
    float* out = (float*)d_out;
    float* W = (float*)d_ws;
    (void)in_sizes; (void)n_in; (void)out_size; (void)ws_size;

    float* Bd_t = W + OFF_BD;
    float* Cm_t = W + OFF_CM;
    float* lAd_ws = W + OFF_LAD;
    float* xq_ws = W + OFF_XQ;
    float* DL_ws = W + OFF_DL;
    float* Acs_ws = W + OFF_ACS;
    float* sred_ws = W + OFF_SRED;
    float* csum_ws = W + OFF_CSUM;
    float* sns_ws = W + OFF_SNS;
    unsigned short* wbh = (unsigned short*)(W + OFF_WBH);
    unsigned short* wbl = (unsigned short*)(W + OFF_WBL);

    k_prep<<<dim3((Kn * CHP * Fn + 255) / 256), dim3(256), 0, stream>>>(
        conv_w, pass_w, wbh, wbl);
    k_conv<<<dim3(NCn, BSn), dim3(256), 0, stream>>>(
        x, wbh, wbl, conv_b, pass_b, red_w, red_b, dtp,
        Bd_t, Cm_t, lAd_ws, xq_ws, DL_ws);
    k_chunk<<<dim3(NCn / 4, BSn), dim3(256), 0, stream>>>(
        lAd_ws, xq_ws, Bd_t, Acs_ws, sred_ws, csum_ws);
    k_scan<<<dim3(256), dim3(256), 0, stream>>>(sred_ws, csum_ws, sns_ws);
    k_y<<<dim3(NCn / 4, BSn), dim3(256), 0, stream>>>(
        Cm_t, Bd_t, xq_ws, Acs_ws, sns_ws, DL_ws, out);
}

// Round 3
// 200.264 us; speedup vs baseline: 1.4600x; 1.4077x over previous
//
#include <hip/hip_runtime.h>
#include <hip/hip_bf16.h>
#include <math.h>

// T=4096, B=4, S=16 -> BS=64, F=64, CH=97 (16 B | 16 C | 1 A | 64 X), K=5.
// Output: (T, B, S) float32, flat index t*64 + bs.
//
// ROUND 12 (weight-traffic attack on k_conv):
//  - Tile-per-wave ownership: wave wv owns channel tiles {wv, wv+4} (wv2:
//    ct2 + its lo-residual, wv3: ct3+ct6) for ALL 64 rows. Weight fragment
//    loads drop 80 -> 20 per wave (L1/L2 weight traffic 320 KB -> 80 KB per
//    block, was 1.3 GB total for a 70 KB tensor).
//  - All 20 weight fragments hoisted into registers BEFORE x-staging: their
//    L2 latency hides behind staging + the barrier drain. Data dependence
//    forces ~80 VGPRs of weights live (r11's compiler refused a hint-only
//    budget: emitted 48 VGPRs and serialized loads).
//  - Epilogue: cross-wave handoff via zsh (A-channel raw acc, wv2->wv0) and
//    pxl (per-wave X partials); fac distributed by in-wave __shfl. 2 barriers.
//  - k_chunk/k_scan/k_y/k_prep unchanged (validated).

#define Tn 4096
#define BSn 64
#define Fn 64
#define CHn 97
#define CHP 112   // padded channels for MFMA (7 tiles of 16); ch97 = pass_w@k4
#define Kn 5
#define Nn 16
#define NCn 64

typedef __attribute__((ext_vector_type(8))) short bf16x8;
typedef __attribute__((ext_vector_type(4))) float f32x4;

static __device__ __forceinline__ unsigned short f2bf(float v) {
    __hip_bfloat16 b = __float2bfloat16(v);
    return *reinterpret_cast<unsigned short*>(&b);
}
static __device__ __forceinline__ float bf2f(unsigned short u) {
    unsigned v = ((unsigned)u) << 16;
    return __builtin_bit_cast(float, v);
}

// ---------------- workspace layout (float units) ----------------
// end = OFF_WBL + 2560 = 9,592,832 fl = 38,371,328 B < round-1-validated
// 38,413,568 B envelope (hard bound).
#define OFF_BD   0
#define OFF_CM   (OFF_BD + 4194304)
#define OFF_LAD  (OFF_CM + 4194304)
#define OFF_XQ   (OFF_LAD + 262144)
#define OFF_DL   (OFF_XQ + 262144)
#define OFF_ACS  (OFF_DL + 262144)
#define OFF_SRED (OFF_ACS + 262144)
#define OFF_CSUM (OFF_SRED + 65536)
#define OFF_SNS  (OFF_CSUM + 4096)
#define OFF_WBH  (OFF_SNS + 65536)      // bf16 [k][112][64]
#define OFF_WBL  (OFF_WBH + 17920)      // bf16 lo-residual [k][16][64] (ch32..47)

// K0: weight prep. ch<97: conv_w; ch97,k=4: pass_w (Dx-as-GEMM row); else 0.
__global__ __launch_bounds__(256) void k_prep(const float* __restrict__ conv_w,
                                              const float* __restrict__ pass_w,
                                              unsigned short* __restrict__ wbh,
                                              unsigned short* __restrict__ wbl) {
    int idx = blockIdx.x * 256 + threadIdx.x;
    if (idx >= Kn * CHP * Fn) return;
    int f = idx & 63;
    int rest = idx >> 6;
    int ch = rest % CHP;
    int k = rest / CHP;
    float w = 0.f;
    if (ch < CHn) w = conv_w[(ch * Fn + f) * Kn + k];
    else if (ch == 97 && k == 4) w = pass_w[f];
    unsigned short hi = f2bf(w);
    wbh[idx] = hi;
    if (ch >= 32 && ch < 48)
        wbl[(k * 16 + (ch - 32)) * 64 + f] = f2bf(w - bf2f(hi));
}

// K1: MFMA conv, tile-per-wave. Block = (ci, bs), 256 thr = 4 waves.
// wv0: ct0 (Bd) + ct4 (X 64..79)
// wv1: ct1 (Cm) + ct5 (X 80..95)
// wv2: ct2 hi + split-residual (A ch32 f32-exact, X 33..47)
// wv3: ct3 (X 48..63) + ct6 (X ch96, Dx ch97)
__global__ __launch_bounds__(256) void k_conv(
    const float* __restrict__ x, const unsigned short* __restrict__ wbh,
    const unsigned short* __restrict__ wbl,
    const float* __restrict__ conv_b, const float* __restrict__ pass_b,
    const float* __restrict__ red_w, const float* __restrict__ red_b,
    const float* __restrict__ dtp,
    float* __restrict__ Bd_t, float* __restrict__ Cm_t,
    float* __restrict__ lAd_ws, float* __restrict__ xq_ws,
    float* __restrict__ DL_ws) {
    const int ci = blockIdx.x, bs = blockIdx.y;
    const int tid = threadIdx.x;
    const int wv = tid >> 6, lane = tid & 63;
    const int qd = lane >> 4, n = lane & 15;

    __shared__ alignas(16) unsigned short xsb[68 * 72];  // bf16 hi, pitch 72
    __shared__ alignas(16) unsigned short xlo[68 * 72];  // bf16 lo residual
    __shared__ float zsh[64];       // raw A-channel acc (wv2 -> wv0)
    __shared__ float pxl[4][64];    // per-wave X-channel row partials

    // ---- hoisted weight loads: 20 bf16x8 per lane, issued FIRST so their
    // latency hides behind x-staging + the barrier drain.
    const int tB = (wv == 3) ? 6 : wv + 4;               // wv2: unused
    const unsigned short* pBw = (wv == 2) ? wbl : wbh;
    const int sB = (wv == 2) ? 16 : CHP;
    const int cB = (wv == 2) ? 0 : 16 * tB;
    bf16x8 wA[10], wB[10];
#pragma unroll
    for (int s = 0; s < 10; ++s) {
        const int k = s >> 1, f0 = 32 * (s & 1) + qd * 8;
        wA[s] = *(const bf16x8*)&wbh[((k * CHP + 16 * wv + n) << 6) + f0];
        wB[s] = *(const bf16x8*)&pBw[((k * sB + cB + n) << 6) + f0];
    }

    // ---- batched x staging: 5 independent float4 loads -> one wait -> store
    float4 v[5];
#pragma unroll
    for (int it = 0; it < 5; ++it) {
        int idx = tid + it * 256;
        int tt = idx >> 4, fq = (idx & 15) * 4;
        int t = ci * 64 - 4 + tt;
        v[it] = (idx < 68 * 16 && t >= 0)
                    ? *(const float4*)&x[(t * 64 + bs) * 64 + fq]
                    : make_float4(0.f, 0.f, 0.f, 0.f);
    }
#pragma unroll
    for (int it = 0; it < 5; ++it) {
        int idx = tid + it * 256;
        if (idx < 68 * 16) {
            int tt = idx >> 4, fq = (idx & 15) * 4;
            ushort4 h, lo;
            h.x = f2bf(v[it].x); lo.x = f2bf(v[it].x - bf2f(h.x));
            h.y = f2bf(v[it].y); lo.y = f2bf(v[it].y - bf2f(h.y));
            h.z = f2bf(v[it].z); lo.z = f2bf(v[it].z - bf2f(h.z));
            h.w = f2bf(v[it].w); lo.w = f2bf(v[it].w - bf2f(h.w));
            *(ushort4*)&xsb[tt * 72 + fq] = h;
            *(ushort4*)&xlo[tt * 72 + fq] = lo;
        }
    }
    __syncthreads();  // barrier 1 (also drains the hoisted weight loads)

    // ---- MFMA: each wave does all 4 row-groups for its tiles
    f32x4 accA[4], accB[4];
#pragma unroll
    for (int rg = 0; rg < 4; ++rg) {
        accA[rg] = (f32x4){0.f, 0.f, 0.f, 0.f};
        accB[rg] = (f32x4){0.f, 0.f, 0.f, 0.f};
    }
    if (wv == 2) {
#pragma unroll
        for (int s = 0; s < 10; ++s) {
            const int k = s >> 1, f0 = 32 * (s & 1) + qd * 8;
#pragma unroll
            for (int rg = 0; rg < 4; ++rg) {
                bf16x8 av = *(const bf16x8*)&xsb[(16 * rg + n + k) * 72 + f0];
                bf16x8 al = *(const bf16x8*)&xlo[(16 * rg + n + k) * 72 + f0];
                accA[rg] = __builtin_amdgcn_mfma_f32_16x16x32_bf16(av, wA[s], accA[rg], 0, 0, 0);
                accA[rg] = __builtin_amdgcn_mfma_f32_16x16x32_bf16(al, wA[s], accA[rg], 0, 0, 0);
                accA[rg] = __builtin_amdgcn_mfma_f32_16x16x32_bf16(av, wB[s], accA[rg], 0, 0, 0);
            }
        }
    } else {
#pragma unroll
        for (int s = 0; s < 10; ++s) {
            const int k = s >> 1, f0 = 32 * (s & 1) + qd * 8;
#pragma unroll
            for (int rg = 0; rg < 4; ++rg) {
                bf16x8 av = *(const bf16x8*)&xsb[(16 * rg + n + k) * 72 + f0];
                accA[rg] = __builtin_amdgcn_mfma_f32_16x16x32_bf16(av, wA[s], accA[rg], 0, 0, 0);
                accB[rg] = __builtin_amdgcn_mfma_f32_16x16x32_bf16(av, wB[s], accB[rg], 0, 0, 0);
            }
        }
    }

    // ---- pre-barrier epilogue: per-tile activations, X partials, Cm/DL/zsh
    // D layout: row = 16*rg + 4*qd + reg, col = n; channel = 16*ct + n.
    const int cbase = (bs * 64 + ci) * 64;
    float px[4][4];
#pragma unroll
    for (int rg = 0; rg < 4; ++rg)
#pragma unroll
        for (int reg = 0; reg < 4; ++reg) px[rg][reg] = 0.f;

    if (wv == 0) {
        const float cb4 = conv_b[64 + n], rw4 = red_w[31 + n];
#pragma unroll
        for (int rg = 0; rg < 4; ++rg)
#pragma unroll
            for (int reg = 0; reg < 4; ++reg) {
                float z = accB[rg][reg] + cb4;
                px[rg][reg] = (z + 1.f / (1.f + __expf(-z))) * rw4;
            }
    } else if (wv == 1) {
        const float cb1 = conv_b[16 + n];
        const float cb5 = conv_b[80 + n], rw5 = red_w[47 + n];
#pragma unroll
        for (int rg = 0; rg < 4; ++rg)
#pragma unroll
            for (int reg = 0; reg < 4; ++reg) {
                float z1 = accA[rg][reg] + cb1;
                Cm_t[(cbase + 16 * rg + 4 * qd + reg) * 16 + n] =
                    z1 + 1.f / (1.f + __expf(-z1));
                float z5 = accB[rg][reg] + cb5;
                px[rg][reg] = (z5 + 1.f / (1.f + __expf(-z5))) * rw5;
            }
    } else if (wv == 2) {
        const float cb2 = conv_b[32 + n];
        const float rw2 = (n >= 1) ? red_w[n - 1] : 0.f;
#pragma unroll
        for (int rg = 0; rg < 4; ++rg)
#pragma unroll
            for (int reg = 0; reg < 4; ++reg) {
                if (n == 0) zsh[16 * rg + 4 * qd + reg] = accA[rg][reg];
                float z = accA[rg][reg] + cb2;
                px[rg][reg] = (z + 1.f / (1.f + __expf(-z))) * rw2;
            }
    } else {
        const float cb3 = conv_b[48 + n], rw3 = red_w[15 + n];
        const float cb6 = conv_b[96], rw6 = red_w[63];
        const float pb = pass_b[0], rb = red_b[0];
#pragma unroll
        for (int rg = 0; rg < 4; ++rg)
#pragma unroll
            for (int reg = 0; reg < 4; ++reg) {
                float z3 = accA[rg][reg] + cb3;
                px[rg][reg] = (z3 + 1.f / (1.f + __expf(-z3))) * rw3;
                if (n == 0) {  // ch96 is an X channel
                    float z6 = accB[rg][reg] + cb6;
                    px[rg][reg] += (z6 + 1.f / (1.f + __expf(-z6))) * rw6;
                }
                if (n == 1) {  // ch97 = Dx (raw, no conv activation)
                    float Dx = accB[rg][reg] + pb;
                    float DL = (Dx >= 0.f) ? Dx : 0.01f * Dx;
                    DL_ws[bs * Tn + ci * 64 + 16 * rg + 4 * qd + reg] = DL + rb;
                }
            }
    }

    // reduce px over the 16 'n' lanes; n==0 lanes hold 16 row-sums
#pragma unroll
    for (int m = 1; m < 16; m <<= 1)
#pragma unroll
        for (int rg = 0; rg < 4; ++rg)
#pragma unroll
            for (int reg = 0; reg < 4; ++reg)
                px[rg][reg] += __shfl_xor(px[rg][reg], m, 64);
    if (n == 0)
#pragma unroll
        for (int rg = 0; rg < 4; ++rg)
#pragma unroll
            for (int reg = 0; reg < 4; ++reg)
                pxl[wv][16 * rg + 4 * qd + reg] = px[rg][reg];
    __syncthreads();  // barrier 2: zsh + pxl ready

    if (wv == 0) {
        // A transform (row = lane, coalesced) then Bd = a(ct0) * fac[row]
        const float dt = log1pf(expf(dtp[0])) + 0.01f;
        float zA = zsh[lane] + conv_b[32];
        float aA = zA + 1.f / (1.f + __expf(-zA));
        float An = -fabsf(aA);
        float lAd = dt * An;
        lAd_ws[bs * Tn + ci * 64 + lane] = lAd;
        float fl = (__expf(lAd) - 1.f) / (An + 1e-9f);
        const float cb0 = conv_b[n];
#pragma unroll
        for (int rg = 0; rg < 4; ++rg)
#pragma unroll
            for (int reg = 0; reg < 4; ++reg) {
                float z = accA[rg][reg] + cb0;
                float a = z + 1.f / (1.f + __expf(-z));
                float fr = __shfl(fl, 16 * rg + 4 * qd + reg, 64);
                Bd_t[(cbase + 16 * rg + 4 * qd + reg) * 16 + n] = a * fr;
            }
    } else if (wv == 1) {
        xq_ws[bs * Tn + ci * 64 + lane] =
            pxl[0][lane] + pxl[1][lane] + pxl[2][lane] + pxl[3][lane];
    }
}

// K2: per (bs, ci): cumsum of lAd, decay-weighted reduced chunk state.
// Validated round-8 logic verbatim; 4 chunks per block (wave wv = chunk).
__global__ __launch_bounds__(256) void k_chunk(
    const float* __restrict__ lAd_ws, const float* __restrict__ xq_ws,
    const float* __restrict__ Bd_t, float* __restrict__ Acs_ws,
    float* __restrict__ sred_ws, float* __restrict__ csum_ws) {
    const int bs = blockIdx.y;
    const int tid = threadIdx.x, wv = tid >> 6, l = tid & 63;
    const int ci = blockIdx.x * 4 + wv;
    __shared__ float aL[4][64], acs[4][64], vv[4][64];
    __shared__ float Bt[4][64 * 17], part[4][4][16];
    const int base = bs * Tn + ci * 64;

    aL[wv][l] = lAd_ws[base + l];
    const float4* brow = (const float4*)&Bd_t[((bs * 64 + ci) * 64 + l) * 16];
    float4 b0 = brow[0], b1 = brow[1], b2 = brow[2], b3 = brow[3];
    float* bt = &Bt[wv][l * 17];
    bt[0] = b0.x;  bt[1] = b0.y;  bt[2] = b0.z;  bt[3] = b0.w;
    bt[4] = b1.x;  bt[5] = b1.y;  bt[6] = b1.z;  bt[7] = b1.w;
    bt[8] = b2.x;  bt[9] = b2.y;  bt[10] = b2.z; bt[11] = b2.w;
    bt[12] = b3.x; bt[13] = b3.y; bt[14] = b3.z; bt[15] = b3.w;
    __syncthreads();

    float s = 0.f;
    for (int k2 = 0; k2 < 64; ++k2) {
        float a = aL[wv][k2];
        if (k2 <= l) s += a;
    }
    acs[wv][l] = s;
    Acs_ws[base + l] = s;
    __syncthreads();

    float tot = acs[wv][63];
    float ds = __expf(fmaxf(tot - s, -20.f));
    vv[wv][l] = ds * xq_ws[base + l];
    __syncthreads();

    int nn = l & 15, q = l >> 4;
    float p = 0.f;
#pragma unroll
    for (int i = 0; i < 16; ++i)
        p += Bt[wv][(q * 16 + i) * 17 + nn] * vv[wv][q * 16 + i];
    part[wv][q][nn] = p;
    __syncthreads();
    if (l < 16)
        sred_ws[(bs * 64 + ci) * 16 + l] =
            part[wv][0][l] + part[wv][1][l] + part[wv][2][l] + part[wv][3][l];
    if (l == 0) csum_ws[bs * 64 + ci] = tot;
}

// K3: inter-chunk scan, wave-parallel. One wave per (bs,n) scan lane; lane ci
// holds the affine map f_ci(x) = d*x + s; 6-step shfl_up composition scan.
__global__ __launch_bounds__(256) void k_scan(const float* __restrict__ sred_ws,
                                              const float* __restrict__ csum_ws,
                                              float* __restrict__ sns_ws) {
    const int wid = blockIdx.x * 4 + (threadIdx.x >> 6);  // 0..1023
    const int ci = threadIdx.x & 63;
    const int bs = wid >> 4, n = wid & 15;
    float s = sred_ws[(bs * 64 + ci) * 16 + n];
    float d = __expf(csum_ws[bs * 64 + ci]);  // <= 1 (csum <= 0), no overflow
#pragma unroll
    for (int k = 1; k < 64; k <<= 1) {
        float dp = __shfl_up(d, k, 64);
        float sp = __shfl_up(s, k, 64);
        if (ci >= k) {
            s = d * sp + s;  // compose on top of lower segment (old d!)
            d = d * dp;
        }
    }
    float se = __shfl_up(s, 1, 64);
    sns_ws[(bs * 64 + ci) * 16 + n] = (ci == 0) ? 0.f : se;
}

// K4: y[l] = sum_m L[l,m]*(C[l]·B[m])*xq[m] + exp(Acs[l])*(C[l]·sns) + DL
//     (validated, unchanged)
__global__ __launch_bounds__(256) void k_y(
    const float* __restrict__ Cm_t, const float* __restrict__ Bd_t,
    const float* __restrict__ xq_ws, const float* __restrict__ Acs_ws,
    const float* __restrict__ sns_ws, const float* __restrict__ DL_ws,
    float* __restrict__ out) {
    const int bs = blockIdx.y;
    const int tid = threadIdx.x;
    const int wv = tid >> 6, l = tid & 63;
    const int ci = blockIdx.x * 4 + wv;
    __shared__ float Bt[4][64 * 17], xv[4][64], ac[4][64], sn[4][16];
    const int base = bs * Tn + ci * 64;

    xv[wv][l] = xq_ws[base + l];
    ac[wv][l] = Acs_ws[base + l];
    if (l < 16) sn[wv][l] = sns_ws[(bs * 64 + ci) * 16 + l];
    const float4* brow = (const float4*)&Bd_t[((bs * 64 + ci) * 64 + l) * 16];
    float4 b0 = brow[0], b1 = brow[1], b2 = brow[2], b3 = brow[3];
    float* bt = &Bt[wv][l * 17];
    bt[0] = b0.x;  bt[1] = b0.y;  bt[2] = b0.z;  bt[3] = b0.w;
    bt[4] = b1.x;  bt[5] = b1.y;  bt[6] = b1.z;  bt[7] = b1.w;
    bt[8] = b2.x;  bt[9] = b2.y;  bt[10] = b2.z; bt[11] = b2.w;
    bt[12] = b3.x; bt[13] = b3.y; bt[14] = b3.z; bt[15] = b3.w;
    const float4* crow = (const float4*)&Cm_t[((bs * 64 + ci) * 64 + l) * 16];
    float4 c0 = crow[0], c1 = crow[1], c2 = crow[2], c3 = crow[3];
    __syncthreads();

    const float acl = ac[wv][l];
    float y = 0.f;
    for (int m = 0; m < 64; ++m) {
        const float* br = &Bt[wv][m * 17];
        float g = c0.x * br[0] + c0.y * br[1] + c0.z * br[2] + c0.w * br[3] +
                  c1.x * br[4] + c1.y * br[5] + c1.z * br[6] + c1.w * br[7] +
                  c2.x * br[8] + c2.y * br[9] + c2.z * br[10] + c2.w * br[11] +
                  c3.x * br[12] + c3.y * br[13] + c3.z * br[14] + c3.w * br[15];
        float arg = (m <= l) ? fmaxf(acl - ac[wv][m], -20.f) : -20.f;
        y += __expf(arg) * g * xv[wv][m];
    }
    const float* s = sn[wv];
    float go = c0.x * s[0] + c0.y * s[1] + c0.z * s[2] + c0.w * s[3] +
               c1.x * s[4] + c1.y * s[5] + c1.z * s[6] + c1.w * s[7] +
               c2.x * s[8] + c2.y * s[9] + c2.z * s[10] + c2.w * s[11] +
               c3.x * s[12] + c3.y * s[13] + c3.z * s[14] + c3.w * s[15];
    y += __expf(acl) * go;

    out[(ci * 64 + l) * 64 + bs] = y + DL_ws[base + l];
}

extern "C" void kernel_launch(void* const* d_in, const int* in_sizes, int n_in,
                              void* d_out, int out_size, void* d_ws,
                              size_t ws_size, hipStream_t stream) {
    const float* x = (const float*)d_in[0];
    const float* conv_w = (const float*)d_in[1];
    const float* conv_b = (const float*)d_in[2];
    const float* pass_w = (const float*)d_in[3];
    const float* pass_b = (const float*)d_in[4];
    const float* red_w = (const float*)d_in[5];
    const float* red_b = (const float*)d_in[6];
    const float* dtp = (const float*)d_in[7];
    float* out = (float*)d_out;
    float* W = (float*)d_ws;
    (void)in_sizes; (void)n_in; (void)out_size; (void)ws_size;

    float* Bd_t = W + OFF_BD;
    float* Cm_t = W + OFF_CM;
    float* lAd_ws = W + OFF_LAD;
    float* xq_ws = W + OFF_XQ;
    float* DL_ws = W + OFF_DL;
    float* Acs_ws = W + OFF_ACS;
    float* sred_ws = W + OFF_SRED;
    float* csum_ws = W + OFF_CSUM;
    float* sns_ws = W + OFF_SNS;
    unsigned short* wbh = (unsigned short*)(W + OFF_WBH);
    unsigned short* wbl = (unsigned short*)(W + OFF_WBL);

    k_prep<<<dim3((Kn * CHP * Fn + 255) / 256), dim3(256), 0, stream>>>(
        conv_w, pass_w, wbh, wbl);
    k_conv<<<dim3(NCn, BSn), dim3(256), 0, stream>>>(
        x, wbh, wbl, conv_b, pass_b, red_w, red_b, dtp,
        Bd_t, Cm_t, lAd_ws, xq_ws, DL_ws);
    k_chunk<<<dim3(NCn / 4, BSn), dim3(256), 0, stream>>>(
        lAd_ws, xq_ws, Bd_t, Acs_ws, sred_ws, csum_ws);
    k_scan<<<dim3(256), dim3(256), 0, stream>>>(sred_ws, csum_ws, sns_ws);
    k_y<<<dim3(NCn / 4, BSn), dim3(256), 0, stream>>>(
        Cm_t, Bd_t, xq_ws, Acs_ws, sns_ws, DL_ws, out);
}